// Round 1
// baseline (208.876 us; speedup 1.0000x reference)
//
#include <hip/hip_runtime.h>
#include <math.h>

// PVConv2d: out = exp0(relu(conv3x3(log0(x), W) + bias)), Poincare ball c=0.01.
// x: [4,32,256,256] f32, Wk: [9,32,32] f32 ([k][o][c]), bias: [32] f32.
// Tile: 32x8 pixels/block, halo 34x10 staged in LDS (stride 33 = conflict-free).
// Wave w -> out channels [8w,8w+8); lane -> 4 pixels; W via wave-uniform s_load.

#define TW 32
#define TH 8
#define HW_ 34
#define HH_ 10
#define NPIX (HW_ * HH_)   // 340
#define LSTR 33
#define CIN 32
#define COUT 32

__global__ __launch_bounds__(256) void pvconv_kernel(
    const float* __restrict__ x, const float* __restrict__ Wk,
    const float* __restrict__ bias, float* __restrict__ out)
{
    __shared__ float lds[NPIX * LSTR];   // 44,880 B

    const int t  = threadIdx.x;
    const int bx = blockIdx.x;   // 8 tiles along w
    const int by = blockIdx.y;   // 32 tiles along h
    const int b  = blockIdx.z;   // batch
    const int x0 = bx * TW, y0 = by * TH;

    // ---- stage halo (raw x, NCHW global) into LDS [pix][c] ----
    for (int c = 0; c < CIN; ++c) {
        const float* xc = x + ((size_t)(b * CIN + c)) * 256 * 256;
        for (int p = t; p < NPIX; p += 256) {
            int py = p / HW_, px = p % HW_;
            int gy = y0 - 1 + py, gx = x0 - 1 + px;
            float v = 0.f;
            if ((unsigned)gy < 256u && (unsigned)gx < 256u)
                v = xc[gy * 256 + gx];
            lds[p * LSTR + c] = v;
        }
    }
    __syncthreads();

    // ---- log0 in place per halo pixel ----
    for (int p = t; p < NPIX; p += 256) {
        float* up = &lds[p * LSTR];
        float ss = 0.f;
        #pragma unroll
        for (int c = 0; c < CIN; ++c) { float v = up[c]; ss = fmaf(v, v, ss); }
        float n = fmaxf(sqrtf(ss), 1e-7f);
        float z = fminf(0.1f * n, 1.f - 1e-6f);
        float at = 0.5f * logf((1.f + z) / (1.f - z));   // artanh(z)
        float s = at / (0.1f * n);
        #pragma unroll
        for (int c = 0; c < CIN; ++c) up[c] *= s;
    }
    __syncthreads();

    // ---- conv GEMM: wave -> o-chunk, lane -> 4 pixels ----
    const int wv   = __builtin_amdgcn_readfirstlane(t >> 6);  // force uniform -> s_load for W
    const int lane = t & 63;
    const int o0   = wv * 8;

    float acc[4][8];
    #pragma unroll
    for (int j = 0; j < 4; ++j)
        #pragma unroll
        for (int oi = 0; oi < 8; ++oi) acc[j][oi] = 0.f;

    int ppx[4], ppy[4];
    #pragma unroll
    for (int j = 0; j < 4; ++j) { int p = lane + 64 * j; ppx[j] = p & 31; ppy[j] = p >> 5; }

    for (int k = 0; k < 9; ++k) {
        const int dy = k / 3, dx = k % 3;
        #pragma unroll
        for (int c8 = 0; c8 < 4; ++c8) {
            float u[4][8];
            #pragma unroll
            for (int j = 0; j < 4; ++j) {
                const float* up = &lds[((ppy[j] + dy) * HW_ + (ppx[j] + dx)) * LSTR + c8 * 8];
                #pragma unroll
                for (int cc = 0; cc < 8; ++cc) u[j][cc] = up[cc];
            }
            #pragma unroll
            for (int oi = 0; oi < 8; ++oi) {
                const float* wp = Wk + ((size_t)(k * COUT + (o0 + oi))) * CIN + c8 * 8;
                #pragma unroll
                for (int cc = 0; cc < 8; ++cc) {
                    const float wcc = wp[cc];        // wave-uniform -> SGPR
                    #pragma unroll
                    for (int j = 0; j < 4; ++j)
                        acc[j][oi] = fmaf(u[j][cc], wcc, acc[j][oi]);
                }
            }
        }
    }
    __syncthreads();   // before reusing lds for v

    // ---- bias + relu, scatter v to lds [pix][o] ----
    #pragma unroll
    for (int j = 0; j < 4; ++j) {
        int p = lane + 64 * j;
        #pragma unroll
        for (int oi = 0; oi < 8; ++oi) {
            float v = acc[j][oi] + bias[o0 + oi];
            lds[p * LSTR + o0 + oi] = fmaxf(v, 0.f);
        }
    }
    __syncthreads();

    // ---- exp0 + coalesced NCHW store (thread t -> pixel t) ----
    {
        const int p = t;
        const int px = p & 31, py = p >> 5;
        const float* vp = &lds[p * LSTR];
        float ss = 0.f;
        #pragma unroll
        for (int o = 0; o < COUT; ++o) { float v = vp[o]; ss = fmaf(v, v, ss); }
        float n = fmaxf(sqrtf(ss), 1e-7f);
        float s = tanhf(0.1f * n) / (0.1f * n);
        const int gy = y0 + py, gx = x0 + px;
        const size_t base = (size_t)b * COUT * 65536 + (size_t)gy * 256 + gx;
        #pragma unroll
        for (int o = 0; o < COUT; ++o)
            out[base + (size_t)o * 65536] = s * vp[o];
    }
}

extern "C" void kernel_launch(void* const* d_in, const int* in_sizes, int n_in,
                              void* d_out, int out_size, void* d_ws, size_t ws_size,
                              hipStream_t stream) {
    const float* x    = (const float*)d_in[0];
    const float* Wk   = (const float*)d_in[1];
    const float* bias = (const float*)d_in[2];
    float* out = (float*)d_out;

    dim3 grid(256 / TW, 256 / TH, 4);   // 8 x 32 x 4
    dim3 block(256);
    pvconv_kernel<<<grid, block, 0, stream>>>(x, Wk, bias, out);
}

// Round 2
// 101.200 us; speedup vs baseline: 2.0640x; 2.0640x over previous
//
#include <hip/hip_runtime.h>
#include <math.h>

// PVConv2d: out = exp0(relu(conv3x3(log0(x), W) + bias)), Poincare ball c=0.01.
// x: [4,32,256,256] f32, Wk: [9,32,32] f32 ([k][o][c]), bias: [32] f32.
// R1: conv via mfma_f32_16x16x32_bf16 (K=32=Cin -> 1 MFMA per tap per tile).
// Tile 32x8 out pixels/block; halo 34x10 staged as bf16 u in LDS [pix][40]
// (80B row stride: 16B-aligned b128 frags, <=2-way bank alias = free).
// Wave = 4 M-tiles (64 pixels) x 2 N-tiles (Cout 16+16), 72 MFMA/wave.
// v round-trips LDS (aliases u/W after sync) for cross-channel exp0 norm.

#define TW 32
#define TH 8
#define HW_ 34
#define HH_ 10
#define NPIX 340
#define USTR 40          // bf16 elems per halo-pixel row
#define WSTR 40          // bf16 elems per W row
#define VSTR 33          // f32 elems per v row
#define CIN 32
#define COUT 32

typedef __attribute__((ext_vector_type(8))) short bf16x8;
typedef __attribute__((ext_vector_type(4))) float f32x4;

__device__ inline unsigned short f2bf(float f) {
    unsigned int u = __builtin_bit_cast(unsigned int, f);
    unsigned int r = (u + 0x7FFFu + ((u >> 16) & 1u)) >> 16;   // RNE
    return (unsigned short)r;
}

__global__ __launch_bounds__(256) void pvconv_kernel(
    const float* __restrict__ x, const float* __restrict__ Wk,
    const float* __restrict__ bias, float* __restrict__ out)
{
    // u: 340*40*2 = 27200 B | Wb: 9*32*40*2 = 23040 B | v aliases: 256*33*4 = 33792 B
    __shared__ __align__(16) unsigned char smem[27200 + 23040];
    unsigned short* u  = (unsigned short*)smem;
    unsigned short* Wb = (unsigned short*)(smem + 27200);
    float*          v  = (float*)smem;

    const int t  = threadIdx.x;
    const int bx = blockIdx.x, by = blockIdx.y, b = blockIdx.z;
    const int x0 = bx * TW, y0 = by * TH;

    // ---- W fp32 -> bf16 LDS [tap][o][WSTR] ----
    for (int e = t; e < 9 * 32 * 32; e += 256) {
        int tap = e >> 10, rem = e & 1023, o = rem >> 5, c = rem & 31;
        Wb[(tap * 32 + o) * WSTR + c] = f2bf(Wk[e]);
    }

    // ---- stage halo: global -> regs, log0, bf16 -> LDS u ----
    for (int p = t; p < NPIX; p += 256) {
        int py = p / HW_, px = p - py * HW_;
        int gy = y0 - 1 + py, gx = x0 - 1 + px;
        float vv[CIN];
        if ((unsigned)gy < 256u && (unsigned)gx < 256u) {
            const float* xp = x + (size_t)b * CIN * 65536 + gy * 256 + gx;
            #pragma unroll
            for (int c = 0; c < CIN; ++c) vv[c] = xp[(size_t)c * 65536];
        } else {
            #pragma unroll
            for (int c = 0; c < CIN; ++c) vv[c] = 0.f;
        }
        float ss = 0.f;
        #pragma unroll
        for (int c = 0; c < CIN; ++c) ss = fmaf(vv[c], vv[c], ss);
        float n = fmaxf(sqrtf(ss), 1e-7f);
        float z = fminf(0.1f * n, 1.f - 1e-6f);
        float at = 0.5f * logf((1.f + z) / (1.f - z));   // artanh
        float s = at / (0.1f * n);
        unsigned int packed[16];
        #pragma unroll
        for (int c2 = 0; c2 < 16; ++c2)
            packed[c2] = (unsigned int)f2bf(vv[2 * c2] * s)
                       | ((unsigned int)f2bf(vv[2 * c2 + 1] * s) << 16);
        uint4* dst = (uint4*)&u[p * USTR];               // 80B-aligned
        #pragma unroll
        for (int j = 0; j < 4; ++j) dst[j] = ((uint4*)packed)[j];
    }
    __syncthreads();

    // ---- MFMA conv: wave -> 64 pixels (4 M-tiles), full Cout (2 N-tiles) ----
    const int wv = t >> 6, lane = t & 63;
    const int m = lane & 15, quad = lane >> 4;

    f32x4 acc[2][4];
    #pragma unroll
    for (int n = 0; n < 2; ++n)
        #pragma unroll
        for (int mt = 0; mt < 4; ++mt) acc[n][mt] = (f32x4)0.f;

    int abase[4];
    #pragma unroll
    for (int mt = 0; mt < 4; ++mt) {
        int pb = wv * 64 + mt * 16;            // tile base out-pixel
        int pxb = pb & 31, pyb = pb >> 5;
        abase[mt] = (pyb * HW_ + pxb + m) * USTR + quad * 8;
    }

    #pragma unroll
    for (int tap = 0; tap < 9; ++tap) {
        const int dy = tap / 3, dx = tap - dy * 3;
        const int hoff = (dy * HW_ + dx) * USTR;
        bf16x8 bf0 = *(const bf16x8*)&Wb[(tap * 32 + m) * WSTR + quad * 8];
        bf16x8 bf1 = *(const bf16x8*)&Wb[(tap * 32 + 16 + m) * WSTR + quad * 8];
        #pragma unroll
        for (int mt = 0; mt < 4; ++mt) {
            bf16x8 af = *(const bf16x8*)&u[abase[mt] + hoff];
            acc[0][mt] = __builtin_amdgcn_mfma_f32_16x16x32_bf16(af, bf0, acc[0][mt], 0, 0, 0);
            acc[1][mt] = __builtin_amdgcn_mfma_f32_16x16x32_bf16(af, bf1, acc[1][mt], 0, 0, 0);
        }
    }

    const float bia0 = bias[m], bia1 = bias[16 + m];
    __syncthreads();   // all waves done reading u/Wb before v overwrites

    // ---- bias+relu, scatter v (f32) to LDS [pix][VSTR] ----
    // D layout: col = lane&15 -> out channel, row = quad*4+r -> pixel offset
    #pragma unroll
    for (int n = 0; n < 2; ++n)
        #pragma unroll
        for (int mt = 0; mt < 4; ++mt)
            #pragma unroll
            for (int r = 0; r < 4; ++r) {
                int pix = wv * 64 + mt * 16 + quad * 4 + r;
                int chan = n * 16 + m;
                float val = acc[n][mt][r] + (n ? bia1 : bia0);
                v[pix * VSTR + chan] = fmaxf(val, 0.f);
            }
    __syncthreads();

    // ---- exp0 + coalesced NCHW store: thread t -> out pixel t ----
    {
        const int px = t & 31, py = t >> 5;
        float q[COUT];
        float ss = 0.f;
        #pragma unroll
        for (int o = 0; o < COUT; ++o) { q[o] = v[t * VSTR + o]; ss = fmaf(q[o], q[o], ss); }
        float n = fmaxf(sqrtf(ss), 1e-7f);
        float s = tanhf(0.1f * n) / (0.1f * n);
        const size_t base = (size_t)b * COUT * 65536 + (size_t)(y0 + py) * 256 + (x0 + px);
        #pragma unroll
        for (int o = 0; o < COUT; ++o)
            out[base + (size_t)o * 65536] = s * q[o];
    }
}

extern "C" void kernel_launch(void* const* d_in, const int* in_sizes, int n_in,
                              void* d_out, int out_size, void* d_ws, size_t ws_size,
                              hipStream_t stream) {
    const float* x    = (const float*)d_in[0];
    const float* Wk   = (const float*)d_in[1];
    const float* bias = (const float*)d_in[2];
    float* out = (float*)d_out;

    dim3 grid(256 / TW, 256 / TH, 4);   // 8 x 32 x 4 = 1024 blocks
    dim3 block(256);
    pvconv_kernel<<<grid, block, 0, stream>>>(x, Wk, bias, out);
}

// Round 3
// 97.998 us; speedup vs baseline: 2.1314x; 1.0327x over previous
//
#include <hip/hip_runtime.h>
#include <math.h>

// PVConv2d: out = exp0(relu(conv3x3(log0(x), W) + bias)), Poincare ball c=0.01.
// x: [4,32,256,256] f32, Wk: [9,32,32] f32 ([k][o][c]), bias: [32] f32.
// R2: fit 4 blocks/CU (grid = 1024 = exactly 4/CU -> no tail round).
//   LDS = u 340x64B (21760) + Wb 288x64B (18432) = 40192 B <= 40960.
//   Compact 64B rows + XOR frag swizzle: frag j of row r at r*64 + (j^((r>>1)&3))*16
//   -> every b128 access = 8 distinct 4-bank groups x 2 lanes/quarter-wave (conflict-free).
//   v phase (f32, stride 36) aliases smem after sync: 36864 B, float4 reads conflict-free.

#define TW 32
#define TH 8
#define HW_ 34
#define NPIX 340         // 34 x 10 halo pixels
#define CIN 32
#define COUT 32
#define U_BYTES 21760    // 340 * 64
#define W_ROWS 288       // 9 * 32

typedef __attribute__((ext_vector_type(8))) short bf16x8;
typedef __attribute__((ext_vector_type(4))) float f32x4;

__device__ inline unsigned short f2bf(float f) {
    unsigned int u = __builtin_bit_cast(unsigned int, f);
    unsigned int r = (u + 0x7FFFu + ((u >> 16) & 1u)) >> 16;   // RNE
    return (unsigned short)r;
}

__global__ __launch_bounds__(256, 4) void pvconv_kernel(
    const float* __restrict__ x, const float* __restrict__ Wk,
    const float* __restrict__ bias, float* __restrict__ out)
{
    __shared__ __align__(16) unsigned char smem[U_BYTES + W_ROWS * 64];  // 40192 B
    unsigned char* u8 = smem;               // bf16 u, 64B rows, frag-swizzled
    unsigned char* w8 = smem + U_BYTES;     // bf16 W, 64B rows, frag-swizzled
    float*         v  = (float*)smem;       // f32 v, stride 36 (aliases, phase 2)

    const int t  = threadIdx.x;
    const int bx = blockIdx.x, by = blockIdx.y, b = blockIdx.z;
    const int x0 = bx * TW, y0 = by * TH;

    // ---- W fp32 -> bf16 LDS, one 16B frag per iter, swizzled placement ----
    for (int f = t; f < W_ROWS * 4; f += 256) {
        int r = f >> 2, j = f & 3;
        const float4* src = (const float4*)(Wk + r * 32 + j * 8);
        float4 a = src[0], c = src[1];
        unsigned int pk[4];
        pk[0] = (unsigned int)f2bf(a.x) | ((unsigned int)f2bf(a.y) << 16);
        pk[1] = (unsigned int)f2bf(a.z) | ((unsigned int)f2bf(a.w) << 16);
        pk[2] = (unsigned int)f2bf(c.x) | ((unsigned int)f2bf(c.y) << 16);
        pk[3] = (unsigned int)f2bf(c.z) | ((unsigned int)f2bf(c.w) << 16);
        int sw = j ^ ((r >> 1) & 3);
        *(uint4*)(w8 + r * 64 + sw * 16) = *(uint4*)pk;
    }

    // ---- stage halo: global -> regs, log0, bf16 -> LDS u (swizzled frags) ----
    for (int p = t; p < NPIX; p += 256) {
        int py = p / HW_, px = p - py * HW_;
        int gy = y0 - 1 + py, gx = x0 - 1 + px;
        float vv[CIN];
        if ((unsigned)gy < 256u && (unsigned)gx < 256u) {
            const float* xp = x + (size_t)b * CIN * 65536 + gy * 256 + gx;
            #pragma unroll
            for (int c = 0; c < CIN; ++c) vv[c] = xp[(size_t)c * 65536];
        } else {
            #pragma unroll
            for (int c = 0; c < CIN; ++c) vv[c] = 0.f;
        }
        float ss = 0.f;
        #pragma unroll
        for (int c = 0; c < CIN; ++c) ss = fmaf(vv[c], vv[c], ss);
        float n = fmaxf(sqrtf(ss), 1e-7f);
        float z = fminf(0.1f * n, 1.f - 1e-6f);
        float at = 0.5f * __logf((1.f + z) / (1.f - z));   // artanh(z)
        float s = at / (0.1f * n);
        int swb = (p >> 1) & 3;
        uint4* row = (uint4*)(u8 + p * 64);
        #pragma unroll
        for (int j = 0; j < 4; ++j) {
            unsigned int pk[4];
            #pragma unroll
            for (int w = 0; w < 4; ++w)
                pk[w] = (unsigned int)f2bf(vv[j * 8 + 2 * w] * s)
                      | ((unsigned int)f2bf(vv[j * 8 + 2 * w + 1] * s) << 16);
            row[j ^ swb] = *(uint4*)pk;
        }
    }
    __syncthreads();

    // ---- MFMA conv: wave -> 64 pixels (4 M-tiles) x full Cout (2 N-tiles) ----
    const int wv = t >> 6, lane = t & 63;
    const int m = lane & 15, quad = lane >> 4;

    f32x4 acc[2][4];
    #pragma unroll
    for (int n = 0; n < 2; ++n)
        #pragma unroll
        for (int mt = 0; mt < 4; ++mt) acc[n][mt] = (f32x4)0.f;

    int apix[4];
    #pragma unroll
    for (int mt = 0; mt < 4; ++mt) {
        int pb = wv * 64 + mt * 16;
        apix[mt] = (pb >> 5) * HW_ + (pb & 31) + m;   // halo row index (tap 0,0)
    }

    #pragma unroll
    for (int tap = 0; tap < 9; ++tap) {
        const int dy = tap / 3, dx = tap - dy * 3;
        const int hoff = dy * HW_ + dx;
        int r0 = tap * 32 + m;
        int swB = quad ^ ((r0 >> 1) & 3);             // (r0+16) has same swizzle bits
        bf16x8 bf0 = *(const bf16x8*)(w8 + r0 * 64 + swB * 16);
        bf16x8 bf1 = *(const bf16x8*)(w8 + (r0 + 16) * 64 + swB * 16);
        #pragma unroll
        for (int mt = 0; mt < 4; ++mt) {
            int hp = apix[mt] + hoff;
            bf16x8 af = *(const bf16x8*)(u8 + hp * 64 + ((quad ^ ((hp >> 1) & 3)) << 4));
            acc[0][mt] = __builtin_amdgcn_mfma_f32_16x16x32_bf16(af, bf0, acc[0][mt], 0, 0, 0);
            acc[1][mt] = __builtin_amdgcn_mfma_f32_16x16x32_bf16(af, bf1, acc[1][mt], 0, 0, 0);
        }
    }

    const float bia0 = bias[m], bia1 = bias[16 + m];
    __syncthreads();   // all waves done reading u/Wb before v overwrites

    // ---- bias+relu, scatter v (f32, stride 36) ----
    // D layout: col = lane&15 -> out channel, row = quad*4+r -> pixel offset
    #pragma unroll
    for (int n = 0; n < 2; ++n)
        #pragma unroll
        for (int mt = 0; mt < 4; ++mt)
            #pragma unroll
            for (int r = 0; r < 4; ++r) {
                int pix = wv * 64 + mt * 16 + quad * 4 + r;
                float val = acc[n][mt][r] + (n ? bia1 : bia0);
                v[pix * 36 + n * 16 + m] = fmaxf(val, 0.f);
            }
    __syncthreads();

    // ---- exp0 + coalesced NCHW store: thread t -> out pixel t ----
    {
        float q[COUT];
        const float4* vp = (const float4*)(smem + (size_t)t * 144);
        #pragma unroll
        for (int j = 0; j < 8; ++j) {
            float4 c4 = vp[j];
            q[4 * j] = c4.x; q[4 * j + 1] = c4.y; q[4 * j + 2] = c4.z; q[4 * j + 3] = c4.w;
        }
        float ss = 0.f;
        #pragma unroll
        for (int o = 0; o < COUT; ++o) ss = fmaf(q[o], q[o], ss);
        float n = fmaxf(sqrtf(ss), 1e-7f);
        float a = 0.1f * n;
        float e = __expf(-2.f * a);
        float s = (1.f - e) / ((1.f + e) * a);        // tanh(a)/a
        const int px = t & 31, py = t >> 5;
        const size_t base = (size_t)b * COUT * 65536 + (size_t)(y0 + py) * 256 + (x0 + px);
        #pragma unroll
        for (int o = 0; o < COUT; ++o)
            out[base + (size_t)o * 65536] = s * q[o];
    }
}

extern "C" void kernel_launch(void* const* d_in, const int* in_sizes, int n_in,
                              void* d_out, int out_size, void* d_ws, size_t ws_size,
                              hipStream_t stream) {
    const float* x    = (const float*)d_in[0];
    const float* Wk   = (const float*)d_in[1];
    const float* bias = (const float*)d_in[2];
    float* out = (float*)d_out;

    dim3 grid(256 / TW, 256 / TH, 4);   // 8 x 32 x 4 = 1024 blocks = 4/CU
    dim3 block(256);
    pvconv_kernel<<<grid, block, 0, stream>>>(x, Wk, bias, out);
}